// Round 1
// baseline (266.110 us; speedup 1.0000x reference)
//
#include <hip/hip_runtime.h>

// ---------------- problem constants ----------------
#define BATCH   8
#define LSEQ    1048576          // 1<<20
#define KCONV   500
#define TWIN    2097             // (L-K)/K + 1
#define MROWS   16776            // BATCH*TWIN
#define MPAD    16896            // 132 * 128
#define KDIM    4000             // KCONV * C_IN
#define NDIM    256              // 2 * C_OUT
#define COUT    128

// ---------------- ws layout (bytes) ----------------
#define A_OFF    0ull
#define A_BYTES  ((size_t)MPAD * KDIM * 2)            // 135,168,000
#define WT_OFF   (A_OFF + A_BYTES)
#define WT_BYTES ((size_t)NDIM * KDIM * 2)            // 2,048,000
#define C_OFF    (WT_OFF + WT_BYTES)
#define C_BYTES  ((size_t)MPAD * NDIM * 4)            // 17,301,504
#define POOL_OFF (C_OFF + C_BYTES)                    // 8*128 floats

typedef __attribute__((ext_vector_type(8))) __bf16 bf16x8;
typedef __attribute__((ext_vector_type(4))) float  floatx4;

__device__ inline unsigned short f2bf(float f) {
    union { float f; unsigned u; } c; c.f = f;
    return (unsigned short)((c.u + 0x7FFFu + ((c.u >> 16) & 1u)) >> 16);
}

// ---------------- kernel 1: weight transpose to bf16 [N=256][K=4000], zero pool ----------------
__global__ __launch_bounds__(256) void wprep_kernel(const float* __restrict__ w1,
                                                    const float* __restrict__ w2,
                                                    unsigned short* __restrict__ Wt,
                                                    float* __restrict__ pool) {
    int idx = blockIdx.x * 256 + threadIdx.x;          // 256*4000 = 1,024,000
    if (idx < 1024) pool[idx] = 0.0f;                  // pool is 8*128 floats
    int o  = idx / KDIM;
    int kk = idx - o * KDIM;
    int k  = kk >> 3;
    int e  = kk & 7;
    // Wt[o][k*8+e] = w[o][e][k]  (w: [COUT][8][500])
    float v = (o < COUT) ? w1[(o * 8 + e) * KCONV + k]
                         : w2[((o - COUT) * 8 + e) * KCONV + k];
    Wt[idx] = f2bf(v);
}

// ---------------- kernel 2: embed x -> A bf16 [MPAD][4000], pad rows zeroed ----------------
__global__ __launch_bounds__(256) void embed_kernel(const int* __restrict__ x,
                                                    const float* __restrict__ emb,
                                                    unsigned short* __restrict__ A) {
    int idx = blockIdx.x * 256 + threadIdx.x;          // MPAD*500 = 8,448,000
    int m = idx / KCONV;
    int p = idx - m * KCONV;
    uint4 o;
    if (m < MROWS) {
        int b = m / TWIN;
        int t = m - b * TWIN;
        int v = x[(size_t)b * LSEQ + t * KCONV + p];
        const float4* er = (const float4*)(emb + v * 8);
        float4 e0 = er[0], e1 = er[1];
        o.x = (unsigned)f2bf(e0.x) | ((unsigned)f2bf(e0.y) << 16);
        o.y = (unsigned)f2bf(e0.z) | ((unsigned)f2bf(e0.w) << 16);
        o.z = (unsigned)f2bf(e1.x) | ((unsigned)f2bf(e1.y) << 16);
        o.w = (unsigned)f2bf(e1.z) | ((unsigned)f2bf(e1.w) << 16);
    } else {
        o.x = o.y = o.z = o.w = 0u;                    // zero pad rows -> C pad rows = 0
    }
    *(uint4*)(A + (size_t)m * KDIM + p * 8) = o;       // 16B coalesced
}

// ---------------- kernel 3: GEMM C[MPAD][256] = A[MPAD][4000] x Wt^T ----------------
// m97 structure: BM=128,BN=128,BK=32, 4 waves, each wave 64x64 via 4x4 mfma_16x16x32_bf16.
// Both operands stored [row][k] row-major (A rows = windows, Wt rows = out-channels).
__global__ __launch_bounds__(256) void gemm_kernel(const unsigned short* __restrict__ A,
                                                   const unsigned short* __restrict__ Bt,
                                                   float* __restrict__ C) {
    __shared__ unsigned short As[128 * 32];            // 8 KB, rows of 64 B
    __shared__ unsigned short Bs[128 * 32];            // 8 KB

    const int tid  = threadIdx.x;
    const int lane = tid & 63;
    const int wv   = tid >> 6;
    const int m0   = blockIdx.x * 128;
    const int n0   = blockIdx.y * 128;
    const int wm   = (wv >> 1) * 64;
    const int wn   = (wv & 1) * 64;
    const int r16  = lane & 15;
    const int k8   = (lane >> 4) * 8;

    floatx4 acc[4][4];
#pragma unroll
    for (int i = 0; i < 4; ++i)
#pragma unroll
        for (int j = 0; j < 4; ++j) acc[i][j] = floatx4{0.f, 0.f, 0.f, 0.f};

    const int rowS = wv * 16 + (lane >> 2);            // staging row (+r*64)
    const int colb = (lane & 3) * 16;                  // byte offset within 64B row

    for (int kt = 0; kt < KDIM / 32; ++kt) {
        const size_t kbyte = (size_t)kt * 64;
#pragma unroll
        for (int r = 0; r < 2; ++r) {
            int row = rowS + r * 64;
            const char* ga = (const char*)A + (size_t)(m0 + row) * (KDIM * 2) + kbyte + colb;
            char* la = (char*)As + row * 64 + colb;    // lds dst = wave_base + lane*16
            __builtin_amdgcn_global_load_lds((const __attribute__((address_space(1))) void*)ga,
                                             (__attribute__((address_space(3))) void*)la, 16, 0, 0);
            const char* gb = (const char*)Bt + (size_t)(n0 + row) * (KDIM * 2) + kbyte + colb;
            char* lb = (char*)Bs + row * 64 + colb;
            __builtin_amdgcn_global_load_lds((const __attribute__((address_space(1))) void*)gb,
                                             (__attribute__((address_space(3))) void*)lb, 16, 0, 0);
        }
        __syncthreads();

        bf16x8 af[4], bfr[4];
#pragma unroll
        for (int i = 0; i < 4; ++i)
            af[i] = *(const bf16x8*)(As + (wm + i * 16 + r16) * 32 + k8);
#pragma unroll
        for (int j = 0; j < 4; ++j)
            bfr[j] = *(const bf16x8*)(Bs + (wn + j * 16 + r16) * 32 + k8);
#pragma unroll
        for (int i = 0; i < 4; ++i)
#pragma unroll
            for (int j = 0; j < 4; ++j)
                acc[i][j] = __builtin_amdgcn_mfma_f32_16x16x32_bf16(af[i], bfr[j], acc[i][j], 0, 0, 0);
        __syncthreads();
    }

    // epilogue: C/D layout col=lane&15, row=(lane>>4)*4+reg  (m89/m91-verified)
#pragma unroll
    for (int i = 0; i < 4; ++i) {
        int mbase = m0 + wm + i * 16 + (lane >> 4) * 4;
#pragma unroll
        for (int j = 0; j < 4; ++j) {
            int n = n0 + wn + j * 16 + r16;
#pragma unroll
            for (int rg = 0; rg < 4; ++rg)
                C[(size_t)(mbase + rg) * NDIM + n] = acc[i][j][rg];
        }
    }
}

// ---------------- kernel 4: gate + segmented max over t into pool[b][o] ----------------
__global__ __launch_bounds__(128) void gate_kernel(const float* __restrict__ C,
                                                   const float* __restrict__ b1,
                                                   const float* __restrict__ b2,
                                                   float* __restrict__ pool) {
    int m0 = blockIdx.x * 64;
    int o  = threadIdx.x;                              // 0..127
    float b1v = b1[o], b2v = b2[o];
    float cur = 0.0f;
    int curb  = m0 / TWIN;
    int nextb = (curb + 1) * TWIN;
    int mend  = m0 + 64; if (mend > MROWS) mend = MROWS;
    for (int m = m0; m < mend; ++m) {
        if (m >= nextb) {
            atomicMax((int*)&pool[curb * COUT + o], __float_as_int(cur));
            cur = 0.0f; curb++; nextb += TWIN;
        }
        float c1 = C[(size_t)m * NDIM + o] + b1v;
        float c2 = C[(size_t)m * NDIM + COUT + o] + b2v;
        float g  = fmaxf(c1, 0.0f) * (1.0f / (1.0f + expf(-c2)));  // gated >= 0
        cur = fmaxf(cur, g);
    }
    atomicMax((int*)&pool[curb * COUT + o], __float_as_int(cur));
}

// ---------------- kernel 5: dense head ----------------
__global__ __launch_bounds__(128) void head_kernel(const float* __restrict__ pool,
                                                   const float* __restrict__ wd1,
                                                   const float* __restrict__ bd1,
                                                   const float* __restrict__ wd2,
                                                   const float* __restrict__ bd2,
                                                   float* __restrict__ out) {
    __shared__ float red[BATCH][COUT];
    int j = threadIdx.x;                               // 0..127
    float wj = wd2[j];
#pragma unroll
    for (int b = 0; b < BATCH; ++b) {
        float s = bd1[j];
        for (int i = 0; i < COUT; ++i) s += pool[b * COUT + i] * wd1[j * COUT + i];
        red[b][j] = fmaxf(s, 0.0f) * wj;
    }
    __syncthreads();
    if (j < BATCH) {
        float s = 0.0f;
        for (int i = 0; i < COUT; ++i) s += red[j][i];
        out[j] = 1.0f / (1.0f + expf(-(s + bd2[0])));
    }
}

// ---------------- launch ----------------
extern "C" void kernel_launch(void* const* d_in, const int* in_sizes, int n_in,
                              void* d_out, int out_size, void* d_ws, size_t ws_size,
                              hipStream_t stream) {
    const int*   x   = (const int*)d_in[0];
    const float* emb = (const float*)d_in[1];
    const float* w1  = (const float*)d_in[2];
    const float* b1  = (const float*)d_in[3];
    const float* w2  = (const float*)d_in[4];
    const float* b2  = (const float*)d_in[5];
    const float* wd1 = (const float*)d_in[6];
    const float* bd1 = (const float*)d_in[7];
    const float* wd2 = (const float*)d_in[8];
    const float* bd2 = (const float*)d_in[9];
    float* out = (float*)d_out;

    unsigned short* A    = (unsigned short*)((char*)d_ws + A_OFF);
    unsigned short* Wt   = (unsigned short*)((char*)d_ws + WT_OFF);
    float*          C    = (float*)((char*)d_ws + C_OFF);
    float*          pool = (float*)((char*)d_ws + POOL_OFF);

    wprep_kernel<<<dim3((NDIM * KDIM) / 256), dim3(256), 0, stream>>>(w1, w2, Wt, pool);
    embed_kernel<<<dim3((MPAD * KCONV) / 256), dim3(256), 0, stream>>>(x, emb, A);
    gemm_kernel<<<dim3(MPAD / 128, NDIM / 128), dim3(256), 0, stream>>>(A, Wt, C);
    gate_kernel<<<dim3((MROWS + 63) / 64), dim3(128), 0, stream>>>(C, b1, b2, pool);
    head_kernel<<<dim3(1), dim3(128), 0, stream>>>(pool, wd1, bd1, wd2, bd2, out);
}

// Round 2
// 223.058 us; speedup vs baseline: 1.1930x; 1.1930x over previous
//
#include <hip/hip_runtime.h>

// ---------------- problem constants ----------------
#define BATCH   8
#define LSEQ    1048576          // 1<<20
#define KCONV   500
#define TWIN    2097             // (L-K)/K + 1
#define MROWS   16776            // BATCH*TWIN
#define MPAD    16896            // 132 * 128
#define KDIM    4000             // KCONV * C_IN
#define NDIM    256              // 2 * C_OUT
#define COUT    128

#define SPLITK  5
#define KCH     (KDIM / SPLITK)  // 800 k-elems per split
#define PCH     (KCH / 8)        // 100 byte-positions per split
#define NITER   (KCH / 32)       // 25 BK=32 iterations

// ---------------- ws layout (bytes) ----------------
#define WT_OFF   0ull
#define WT_BYTES ((size_t)NDIM * KDIM * 2)                  // 2,048,000
#define CP_OFF   (WT_OFF + WT_BYTES)
#define CP_BYTES ((size_t)SPLITK * MPAD * NDIM * 4)         // 86,507,520
#define POOL_OFF (CP_OFF + CP_BYTES)                        // 8*128 floats

typedef __attribute__((ext_vector_type(8))) __bf16 bf16x8;
typedef __attribute__((ext_vector_type(4))) float  floatx4;

__device__ inline unsigned short f2bf(float f) {
    union { float f; unsigned u; } c; c.f = f;
    return (unsigned short)((c.u + 0x7FFFu + ((c.u >> 16) & 1u)) >> 16);
}
__device__ inline unsigned pack2(float lo, float hi) {
    return (unsigned)f2bf(lo) | ((unsigned)f2bf(hi) << 16);
}
__device__ inline uint4 pack8(float4 a, float4 b) {
    uint4 r;
    r.x = pack2(a.x, a.y); r.y = pack2(a.z, a.w);
    r.z = pack2(b.x, b.y); r.w = pack2(b.z, b.w);
    return r;
}

// ---------------- kernel 1: weight transpose to bf16 Wt[N=256][K=4000], zero pool ----------------
__global__ __launch_bounds__(256) void wprep_kernel(const float* __restrict__ w1,
                                                    const float* __restrict__ w2,
                                                    unsigned short* __restrict__ Wt,
                                                    float* __restrict__ pool) {
    int idx = blockIdx.x * 256 + threadIdx.x;          // 256*4000 = 1,024,000
    if (idx < 1024) pool[idx] = 0.0f;                  // pool is 8*128 floats
    int o  = idx / KDIM;
    int kk = idx - o * KDIM;
    int k  = kk >> 3;
    int e  = kk & 7;
    // Wt[o][k*8+e] = w[o][e][k]  (w: [COUT][8][500])
    float v = (o < COUT) ? w1[(o * 8 + e) * KCONV + k]
                         : w2[((o - COUT) * 8 + e) * KCONV + k];
    Wt[idx] = f2bf(v);
}

// ---------------- kernel 2: fused embed + split-K GEMM ----------------
// Cp[kc][MPAD][256] partial = A_chunk[MPAD][800] x Wt_chunk^T
// BM=128, BN=128, BK=32, 4 waves each 64x64 via 4x4 mfma_16x16x32_bf16.
// A-tile is built in-register: gather x -> emb (8KB, L1) -> bf16 pack -> ds_write_b128.
// B-tile staged via global_load_lds width=16 from Wt (L2/L3-resident).
__global__ __launch_bounds__(256) void gemm_fused_kernel(const int* __restrict__ x,
                                                         const float* __restrict__ emb,
                                                         const unsigned short* __restrict__ Wt,
                                                         float* __restrict__ Cp) {
    __shared__ unsigned short As[128 * 32];            // 8 KB, rows of 64 B
    __shared__ unsigned short Bs[128 * 32];            // 8 KB

    const int tid  = threadIdx.x;
    const int lane = tid & 63;
    const int wv   = tid >> 6;
    const int m0   = blockIdx.x * 128;
    const int n0   = blockIdx.y * 128;
    const int kc   = blockIdx.z;
    const int wm   = (wv >> 1) * 64;
    const int wn   = (wv & 1) * 64;
    const int r16  = lane & 15;
    const int k8   = (lane >> 4) * 8;

    // A-staging: thread handles (row ar, tile-positions pp..pp+1); fixed across iters
    const int  ar     = tid >> 1;
    const int  pp     = (tid & 1) * 2;
    const int  am     = m0 + ar;
    const bool avalid = (am < MROWS);
    const int  ab     = am / TWIN;
    const int  at     = am - ab * TWIN;
    const int* xrow   = x + ((size_t)ab * LSEQ + (size_t)at * KCONV);
    const int  pbase  = kc * PCH + pp;
    unsigned short* asdst = As + ar * 32 + pp * 8;

    // B-staging mapping (global_load_lds: wave-uniform base + lane*16)
    const int brow  = wv * 16 + (lane >> 2);
    const int bcolb = (lane & 3) * 16;

    floatx4 acc[4][4];
#pragma unroll
    for (int i = 0; i < 4; ++i)
#pragma unroll
        for (int j = 0; j < 4; ++j) acc[i][j] = floatx4{0.f, 0.f, 0.f, 0.f};

    for (int kt = 0; kt < NITER; ++kt) {
        // ---- A: gather + embed + pack ----
        uint4 w0, w1;
        if (avalid) {
            const int p = pbase + kt * 4;              // {p, p+1}, p even -> 8B aligned
            int2 vv = *(const int2*)(xrow + p);
            const float4* e0 = (const float4*)(emb + vv.x * 8);
            const float4* e1 = (const float4*)(emb + vv.y * 8);
            float4 a0 = e0[0], a1 = e0[1];
            float4 b0 = e1[0], b1 = e1[1];
            w0 = pack8(a0, a1);
            w1 = pack8(b0, b1);
        } else {
            w0 = uint4{0u, 0u, 0u, 0u}; w1 = w0;       // zero pad rows
        }
        // ---- B: async global->LDS ----
        const size_t kbyte = (size_t)(kc * KCH + kt * 32) * 2;
#pragma unroll
        for (int r2 = 0; r2 < 2; ++r2) {
            int row = brow + r2 * 64;
            const char* gb = (const char*)Wt + (size_t)(n0 + row) * (KDIM * 2) + kbyte + bcolb;
            char* lb = (char*)Bs + row * 64 + bcolb;
            __builtin_amdgcn_global_load_lds((const __attribute__((address_space(1))) void*)gb,
                                             (__attribute__((address_space(3))) void*)lb, 16, 0, 0);
        }
        *(uint4*)(asdst)     = w0;
        *(uint4*)(asdst + 8) = w1;
        __syncthreads();

        bf16x8 af[4], bfr[4];
#pragma unroll
        for (int i = 0; i < 4; ++i)
            af[i] = *(const bf16x8*)(As + (wm + i * 16 + r16) * 32 + k8);
#pragma unroll
        for (int j = 0; j < 4; ++j)
            bfr[j] = *(const bf16x8*)(Bs + (wn + j * 16 + r16) * 32 + k8);
#pragma unroll
        for (int i = 0; i < 4; ++i)
#pragma unroll
            for (int j = 0; j < 4; ++j)
                acc[i][j] = __builtin_amdgcn_mfma_f32_16x16x32_bf16(af[i], bfr[j], acc[i][j], 0, 0, 0);
        __syncthreads();
    }

    // epilogue: C/D layout col=lane&15, row=(lane>>4)*4+reg (m89/m91-verified)
    float* Cout = Cp + (size_t)kc * MPAD * NDIM;
#pragma unroll
    for (int i = 0; i < 4; ++i) {
        int mbase = m0 + wm + i * 16 + (lane >> 4) * 4;
#pragma unroll
        for (int j = 0; j < 4; ++j) {
            int n = n0 + wn + j * 16 + r16;
#pragma unroll
            for (int rg = 0; rg < 4; ++rg)
                Cout[(size_t)(mbase + rg) * NDIM + n] = acc[i][j][rg];
        }
    }
}

// ---------------- kernel 3: 5-way partial sum + gate + segmented max into pool[b][o] ----------------
__global__ __launch_bounds__(128) void gate_kernel(const float* __restrict__ Cp,
                                                   const float* __restrict__ b1,
                                                   const float* __restrict__ b2,
                                                   float* __restrict__ pool) {
    int m0 = blockIdx.x * 32;
    int o  = threadIdx.x;                              // 0..127
    float b1v = b1[o], b2v = b2[o];
    float cur = 0.0f;
    int curb  = m0 / TWIN;
    int nextb = (curb + 1) * TWIN;
    int mend  = m0 + 32; if (mend > MROWS) mend = MROWS;
    for (int m = m0; m < mend; ++m) {
        if (m >= nextb) {
            atomicMax((int*)&pool[curb * COUT + o], __float_as_int(cur));
            cur = 0.0f; curb++; nextb += TWIN;
        }
        float c1 = b1v, c2 = b2v;
#pragma unroll
        for (int s = 0; s < SPLITK; ++s) {
            c1 += Cp[(size_t)s * MPAD * NDIM + (size_t)m * NDIM + o];
            c2 += Cp[(size_t)s * MPAD * NDIM + (size_t)m * NDIM + COUT + o];
        }
        float g = fmaxf(c1, 0.0f) * (1.0f / (1.0f + expf(-c2)));  // gated >= 0
        cur = fmaxf(cur, g);
    }
    atomicMax((int*)&pool[curb * COUT + o], __float_as_int(cur));
}

// ---------------- kernel 4: dense head ----------------
__global__ __launch_bounds__(128) void head_kernel(const float* __restrict__ pool,
                                                   const float* __restrict__ wd1,
                                                   const float* __restrict__ bd1,
                                                   const float* __restrict__ wd2,
                                                   const float* __restrict__ bd2,
                                                   float* __restrict__ out) {
    __shared__ float red[BATCH][COUT];
    int j = threadIdx.x;                               // 0..127
    float wj = wd2[j];
#pragma unroll
    for (int b = 0; b < BATCH; ++b) {
        float s = bd1[j];
        for (int i = 0; i < COUT; ++i) s += pool[b * COUT + i] * wd1[j * COUT + i];
        red[b][j] = fmaxf(s, 0.0f) * wj;
    }
    __syncthreads();
    if (j < BATCH) {
        float s = 0.0f;
        for (int i = 0; i < COUT; ++i) s += red[j][i];
        out[j] = 1.0f / (1.0f + expf(-(s + bd2[0])));
    }
}

// ---------------- launch ----------------
extern "C" void kernel_launch(void* const* d_in, const int* in_sizes, int n_in,
                              void* d_out, int out_size, void* d_ws, size_t ws_size,
                              hipStream_t stream) {
    const int*   x   = (const int*)d_in[0];
    const float* emb = (const float*)d_in[1];
    const float* w1  = (const float*)d_in[2];
    const float* b1  = (const float*)d_in[3];
    const float* w2  = (const float*)d_in[4];
    const float* b2  = (const float*)d_in[5];
    const float* wd1 = (const float*)d_in[6];
    const float* bd1 = (const float*)d_in[7];
    const float* wd2 = (const float*)d_in[8];
    const float* bd2 = (const float*)d_in[9];
    float* out = (float*)d_out;

    unsigned short* Wt   = (unsigned short*)((char*)d_ws + WT_OFF);
    float*          Cp   = (float*)((char*)d_ws + CP_OFF);
    float*          pool = (float*)((char*)d_ws + POOL_OFF);

    wprep_kernel<<<dim3((NDIM * KDIM) / 256), dim3(256), 0, stream>>>(w1, w2, Wt, pool);
    gemm_fused_kernel<<<dim3(MPAD / 128, NDIM / 128, SPLITK), dim3(256), 0, stream>>>(x, emb, Wt, Cp);
    gate_kernel<<<dim3((MROWS + 31) / 32), dim3(128), 0, stream>>>(Cp, b1, b2, pool);
    head_kernel<<<dim3(1), dim3(128), 0, stream>>>(pool, wd1, bd1, wd2, bd2, out);
}

// Round 3
// 194.898 us; speedup vs baseline: 1.3654x; 1.1445x over previous
//
#include <hip/hip_runtime.h>

// ---------------- problem constants ----------------
#define BATCH   8
#define LSEQ    1048576          // 1<<20
#define KCONV   500
#define TWIN    2097             // (L-K)/K + 1
#define MROWS   16776            // BATCH*TWIN
#define MPAD    16896            // 264 * 64
#define KDIM    4000             // KCONV * C_IN
#define NDIM    256              // 2 * C_OUT
#define COUT    128
#define VOCABP  256              // padding row of emb (all zeros)

#define SPLITK  5
#define KCH     (KDIM / SPLITK)  // 800 k-elems per split
#define PCH     (KCH / 8)        // 100 positions per split
#define NITER   (KCH / 32)       // 25 BK=32 iterations
#define BM      64               // rows per block; BN = NDIM = 256 (full N)

// ---------------- ws layout (bytes) ----------------
#define WT_OFF   0ull
#define WT_BYTES ((size_t)NDIM * KDIM * 2)                  // 2,048,000
#define CP_OFF   (WT_OFF + WT_BYTES)
#define CP_BYTES ((size_t)SPLITK * NDIM * MPAD * 2)         // 43,253,760 (bf16, [kc][n][m])
#define POOL_OFF (CP_OFF + CP_BYTES)                        // 8*128 floats

typedef __attribute__((ext_vector_type(8))) __bf16 bf16x8;
typedef __attribute__((ext_vector_type(4))) float  floatx4;

__device__ inline unsigned short f2bf(float f) {
    union { float f; unsigned u; } c; c.f = f;
    return (unsigned short)((c.u + 0x7FFFu + ((c.u >> 16) & 1u)) >> 16);
}
__device__ inline unsigned pack2(float lo, float hi) {
    return (unsigned)f2bf(lo) | ((unsigned)f2bf(hi) << 16);
}
__device__ inline uint4 pack8(float4 a, float4 b) {
    uint4 r;
    r.x = pack2(a.x, a.y); r.y = pack2(a.z, a.w);
    r.z = pack2(b.x, b.y); r.w = pack2(b.z, b.w);
    return r;
}
__device__ inline float bf2f(unsigned short u) {
    return __uint_as_float((unsigned)u << 16);
}

// ---------------- kernel 1: weight transpose to bf16 Wt[N=256][K=4000] ----------------
__global__ __launch_bounds__(256) void wprep_kernel(const float* __restrict__ w1,
                                                    const float* __restrict__ w2,
                                                    unsigned short* __restrict__ Wt) {
    int idx = blockIdx.x * 256 + threadIdx.x;          // 256*4000 = 1,024,000
    int o  = idx / KDIM;
    int kk = idx - o * KDIM;
    int k  = kk >> 3;
    int e  = kk & 7;
    // Wt[o][k*8+e] = w[o][e][k]  (w: [COUT][8][500])
    float v = (o < COUT) ? w1[(o * 8 + e) * KCONV + k]
                         : w2[((o - COUT) * 8 + e) * KCONV + k];
    Wt[idx] = f2bf(v);
}

// ---------------- kernel 2: fused embed + split-K GEMM, double-buffered ----------------
// Cp[kc][n][m] (bf16) partial = A_chunk[MPAD][800] x Wt_chunk^T
// BM=64, BN=256, BK=32. 4 waves, each computes 64(m) x 64(n) via 4x4 mfma_16x16x32_bf16.
// A-tile built in-register (x gather -> emb (8KB, L1) -> pack -> conflict-free ds_write_b128),
// B-tile via global_load_lds width=16. LDS double-buffered, ONE barrier per iteration:
// next iter's B-loads issue at iter start so the vmcnt(0) drain at the barrier is covered.
__global__ __launch_bounds__(256, 4) void gemm_fused_kernel(const int* __restrict__ x,
                                                            const float* __restrict__ emb,
                                                            const unsigned short* __restrict__ Wt,
                                                            unsigned short* __restrict__ Cp) {
    __shared__ unsigned short As[2][BM * 32];          // 2 x 4 KB
    __shared__ unsigned short Bs[2][NDIM * 32];        // 2 x 16 KB

    const int tid  = threadIdx.x;
    const int lane = tid & 63;
    const int wv   = tid >> 6;
    const int m0   = blockIdx.x * BM;
    const int kc   = blockIdx.y;
    const int r16  = lane & 15;
    const int k8   = (lane >> 4) * 8;                  // shorts

    // ---- A staging role: thread -> (row ar, position chunk pc) ----
    const int  ar     = tid >> 2;                      // 0..63
    const int  pc     = tid & 3;                       // position within BK (BK=32 = 4 pos x 8 dims)
    const int  am     = m0 + ar;
    const bool avalid = (am < MROWS);
    const int  amc    = avalid ? am : 0;
    const int  ab     = amc / TWIN;
    const int  at     = amc - ab * TWIN;
    const int* xp     = x + ((size_t)ab * LSEQ + (size_t)at * KCONV + kc * PCH + pc);
    unsigned short* ad0 = &As[0][ar * 32 + pc * 8];
    unsigned short* ad1 = &As[1][ar * 32 + pc * 8];

    // ---- B staging role (global_load_lds: dst == wave-uniform base + lane*16) ----
    const int bro = lane >> 2;                         // row within 16-row segment
    const int bco = (lane & 3) * 16;                   // byte col within 64B row

    floatx4 acc[4][4];
#pragma unroll
    for (int i = 0; i < 4; ++i)
#pragma unroll
        for (int j = 0; j < 4; ++j) acc[i][j] = floatx4{0.f, 0.f, 0.f, 0.f};

    // ---- prologue: stage kt=0 into buffer 0 ----
    {
        const size_t kbyte = (size_t)(kc * KCH) * 2;
#pragma unroll
        for (int r = 0; r < 4; ++r) {
            const int row = r * 64 + wv * 16 + bro;
            const char* g = (const char*)Wt + (size_t)row * (KDIM * 2) + kbyte + bco;
            char* l = (char*)&Bs[0][0] + (size_t)row * 64 + bco;
            __builtin_amdgcn_global_load_lds((const __attribute__((address_space(1))) void*)g,
                                             (__attribute__((address_space(3))) void*)l, 16, 0, 0);
        }
        int v0 = avalid ? xp[0] : VOCABP;              // emb[256] is the zero row
        const float4* er = (const float4*)(emb + v0 * 8);
        *(uint4*)ad0 = pack8(er[0], er[1]);
    }
    int vnext = (avalid && NITER > 1) ? xp[4] : VOCABP;   // x value feeding stage of kt=1
    __syncthreads();

    for (int kt = 0; kt < NITER; ++kt) {
        const int  cur  = kt & 1;
        const bool more = (kt + 1 < NITER);

        // issue next B-tile loads first (latency covered by rest of the iteration)
        if (more) {
            const size_t kbyte = (size_t)(kc * KCH + (kt + 1) * 32) * 2;
            char* bbase = (char*)&Bs[cur ^ 1][0];
#pragma unroll
            for (int r = 0; r < 4; ++r) {
                const int row = r * 64 + wv * 16 + bro;
                const char* g = (const char*)Wt + (size_t)row * (KDIM * 2) + kbyte + bco;
                char* l = bbase + (size_t)row * 64 + bco;
                __builtin_amdgcn_global_load_lds((const __attribute__((address_space(1))) void*)g,
                                                 (__attribute__((address_space(3))) void*)l, 16, 0, 0);
            }
        }
        // prefetch x two iterations ahead
        int v2 = VOCABP;
        if (avalid && kt + 2 < NITER) v2 = xp[(kt + 2) * 4];
        // emb gather for NEXT iteration (vnext was loaded last iteration)
        float4 e0, e1;
        if (more) {
            const float4* er = (const float4*)(emb + vnext * 8);
            e0 = er[0]; e1 = er[1];
        }

        // consume current buffers
        bf16x8 af[4], bfr[4];
        const unsigned short* ac = &As[cur][0];
        const unsigned short* bc = &Bs[cur][0];
#pragma unroll
        for (int i = 0; i < 4; ++i)
            af[i] = *(const bf16x8*)(ac + (i * 16 + r16) * 32 + k8);
#pragma unroll
        for (int j = 0; j < 4; ++j)
            bfr[j] = *(const bf16x8*)(bc + (wv * 64 + j * 16 + r16) * 32 + k8);
#pragma unroll
        for (int i = 0; i < 4; ++i)
#pragma unroll
            for (int j = 0; j < 4; ++j)
                acc[i][j] = __builtin_amdgcn_mfma_f32_16x16x32_bf16(af[i], bfr[j], acc[i][j], 0, 0, 0);

        // write next A-tile (other buffer; racing nothing — reads above hit `cur`)
        if (more)
            *(uint4*)((cur ^ 1) ? ad1 : ad0) = pack8(e0, e1);
        vnext = v2;
        __syncthreads();                                // single barrier per iteration
    }

    // ---- epilogue: Cp[kc][n][m] bf16; lane holds 4 consecutive m at fixed n ----
    unsigned short* Cout = Cp + (size_t)kc * NDIM * MPAD;
#pragma unroll
    for (int i = 0; i < 4; ++i) {
        const int mb = m0 + i * 16 + (lane >> 4) * 4;   // C/D layout: col=lane&15, row=(lane>>4)*4+reg
#pragma unroll
        for (int j = 0; j < 4; ++j) {
            const int n = wv * 64 + j * 16 + r16;
            uint2 u;
            u.x = pack2(acc[i][j][0], acc[i][j][1]);
            u.y = pack2(acc[i][j][2], acc[i][j][3]);
            *(uint2*)(Cout + (size_t)n * MPAD + mb) = u;
        }
    }
}

// ---------------- kernel 3: split-sum + gate + max over t, one block per (o,b) ----------------
__global__ __launch_bounds__(256) void gate_kernel(const unsigned short* __restrict__ Cp,
                                                   const float* __restrict__ b1,
                                                   const float* __restrict__ b2,
                                                   float* __restrict__ pool) {
    const int o = blockIdx.x;                          // 0..127
    const int b = blockIdx.y;                          // 0..7
    const int t = threadIdx.x;                         // 0..255
    const float b1v = b1[o], b2v = b2[o];
    const size_t mb = (size_t)b * TWIN;
    const unsigned short* s1[SPLITK];
    const unsigned short* s2[SPLITK];
#pragma unroll
    for (int s = 0; s < SPLITK; ++s) {
        s1[s] = Cp + ((size_t)s * NDIM + o) * MPAD + mb;
        s2[s] = Cp + ((size_t)s * NDIM + o + COUT) * MPAD + mb;
    }
    float gmax = 0.0f;                                 // gated = relu*sigmoid >= 0
    for (int m = t; m < TWIN; m += 256) {              // stride-1 across lanes: coalesced
        float c1 = b1v, c2 = b2v;
#pragma unroll
        for (int s = 0; s < SPLITK; ++s) {
            c1 += bf2f(s1[s][m]);
            c2 += bf2f(s2[s][m]);
        }
        float g = fmaxf(c1, 0.0f) / (1.0f + __expf(-c2));
        gmax = fmaxf(gmax, g);
    }
    __shared__ float red[256];
    red[t] = gmax;
    __syncthreads();
#pragma unroll
    for (int s = 128; s > 0; s >>= 1) {
        if (t < s) red[t] = fmaxf(red[t], red[t + s]);
        __syncthreads();
    }
    if (t == 0) pool[b * COUT + o] = red[0];
}

// ---------------- kernel 4: dense head ----------------
__global__ __launch_bounds__(128) void head_kernel(const float* __restrict__ pool,
                                                   const float* __restrict__ wd1,
                                                   const float* __restrict__ bd1,
                                                   const float* __restrict__ wd2,
                                                   const float* __restrict__ bd2,
                                                   float* __restrict__ out) {
    __shared__ float red[BATCH][COUT];
    int j = threadIdx.x;                               // 0..127
    float wj = wd2[j];
#pragma unroll
    for (int b = 0; b < BATCH; ++b) {
        float s = bd1[j];
        for (int i = 0; i < COUT; ++i) s += pool[b * COUT + i] * wd1[j * COUT + i];
        red[b][j] = fmaxf(s, 0.0f) * wj;
    }
    __syncthreads();
    if (j < BATCH) {
        float s = 0.0f;
        for (int i = 0; i < COUT; ++i) s += red[j][i];
        out[j] = 1.0f / (1.0f + expf(-(s + bd2[0])));
    }
}

// ---------------- launch ----------------
extern "C" void kernel_launch(void* const* d_in, const int* in_sizes, int n_in,
                              void* d_out, int out_size, void* d_ws, size_t ws_size,
                              hipStream_t stream) {
    const int*   x   = (const int*)d_in[0];
    const float* emb = (const float*)d_in[1];
    const float* w1  = (const float*)d_in[2];
    const float* b1  = (const float*)d_in[3];
    const float* w2  = (const float*)d_in[4];
    const float* b2  = (const float*)d_in[5];
    const float* wd1 = (const float*)d_in[6];
    const float* bd1 = (const float*)d_in[7];
    const float* wd2 = (const float*)d_in[8];
    const float* bd2 = (const float*)d_in[9];
    float* out = (float*)d_out;

    unsigned short* Wt   = (unsigned short*)((char*)d_ws + WT_OFF);
    unsigned short* Cp   = (unsigned short*)((char*)d_ws + CP_OFF);
    float*          pool = (float*)((char*)d_ws + POOL_OFF);

    wprep_kernel<<<dim3((NDIM * KDIM) / 256), dim3(256), 0, stream>>>(w1, w2, Wt);
    gemm_fused_kernel<<<dim3(MPAD / BM, SPLITK), dim3(256), 0, stream>>>(x, emb, Wt, Cp);
    gate_kernel<<<dim3(COUT, BATCH), dim3(256), 0, stream>>>(Cp, b1, b2, pool);
    head_kernel<<<dim3(1), dim3(128), 0, stream>>>(pool, wd1, bd1, wd2, bd2, out);
}